// Round 13
// baseline (147.709 us; speedup 1.0000x reference)
//
#include <hip/hip_runtime.h>
#include <math.h>

#define BB 4
#define CC 128
#define WWW 256
#define HWSZ 65536          // 256*256 elems per (b,c) slice
#define HIDDEN 16
#define NPAIR 8192          // float4-pairs per b-image
#define FCHUNK 16           // pairs per fused block
#define NFCHUNK (NPAIR/FCHUNK)   // 512
#define RQUART 4            // reduce blocks per (b,c)
#define RBLK_PER_B (CC*RQUART)   // 512 reduce blocks per image

typedef float nfloat4 __attribute__((ext_vector_type(4)));

// EXACTLY 16 floats = 64 B
struct CParams {
    float thr0, thr1, thr2;   // 2*sigmoid(theta)*m  (thresholds for UNSCALED bands)
    float gA0, gA1, gA2;      // sigmoid(dir_gate)   (attn path)
    float gF0, gF1, gF2;      // 0.5*g*wse2          (final path, folded)
    float wsm, e0q;           // softmax weight; 0.25*wse2
    float ca, cb, cc, cd;     // 0.5 * idwt sign-combos of w_redis
    float pad0;
};
static_assert(sizeof(CParams) == 64, "CParams must be 64B");

__device__ __forceinline__ float sigmoidf_(float v) { return 1.0f / (1.0f + expf(-v)); }

// ---- Kernel 1: per-(b,c) partial reductions + last-block-per-b computes params ----
__global__ __launch_bounds__(256) void k_reduce(const float* __restrict__ x,
                                                float4* __restrict__ partial,
                                                unsigned int* __restrict__ counters,
    const float* __restrict__ theta, const float* __restrict__ dir_gate,
    const float* __restrict__ fc_w, const float* __restrict__ fc_b,
    const float* __restrict__ sub_r,
    const float* __restrict__ se_w1, const float* __restrict__ se_b1,
    const float* __restrict__ se_w2, const float* __restrict__ se_b2,
    const float* __restrict__ gamma_p,
    CParams* __restrict__ cbuf) {
    const int bq = blockIdx.x;                  // 0..2047
    const int bc = bq >> 2;
    const int quarter = bq & 3;
    const int b = bq >> 9;                      // image 0..3
    const float* base = x + (size_t)bc * HWSZ;
    const int tid = threadIdx.x;
    float a0 = 0.f, a1 = 0.f, a2 = 0.f, sx = 0.f;
    #pragma unroll
    for (int i = 0; i < 8; ++i) {
        const int p = quarter * 2048 + i * 256 + tid;   // 0..8191
        const int r = p >> 6;
        const int q = p & 63;
        const float4 t  = *(const float4*)(base + (2*r)   * WWW + 4*q);
        const float4 bo = *(const float4*)(base + (2*r+1) * WWW + 4*q);
        {   const float a = t.x, b_ = t.y, c_ = bo.x, d = bo.y;
            const float u1 = a + b_, u2 = c_ + d, u3 = a + c_, u4 = b_ + d, u5 = a + d, u6 = b_ + c_;
            a0 += fabsf(u4 - u3);   // |2LH|
            a1 += fabsf(u2 - u1);   // |2HL|
            a2 += fabsf(u5 - u6);   // |2HH|
            sx += u1 + u2;
        }
        {   const float a = t.z, b_ = t.w, c_ = bo.z, d = bo.w;
            const float u1 = a + b_, u2 = c_ + d, u3 = a + c_, u4 = b_ + d, u5 = a + d, u6 = b_ + c_;
            a0 += fabsf(u4 - u3);
            a1 += fabsf(u2 - u1);
            a2 += fabsf(u5 - u6);
            sx += u1 + u2;
        }
    }
    __shared__ float4 red[256];
    red[tid] = make_float4(a0, a1, a2, sx);
    __syncthreads();
    for (int off = 128; off > 0; off >>= 1) {
        if (tid < off) {
            float4 o = red[tid + off];
            red[tid].x += o.x; red[tid].y += o.y; red[tid].z += o.z; red[tid].w += o.w;
        }
        __syncthreads();
    }
    __shared__ int is_last;
    if (tid == 0) {
        partial[bq] = red[0];
        __threadfence();                            // release partial (device scope)
        const unsigned int old = atomicAdd(&counters[b], 1u);
        is_last = (old == RBLK_PER_B - 1) ? 1 : 0;
    }
    __syncthreads();
    if (!is_last) return;
    __threadfence();                                // acquire all partials for this b

    // ---- params for image b (verbatim old k_params math; threads 0..127) ----
    __shared__ float gap[CC];
    __shared__ float z1[HIDDEN];
    __shared__ float yv[CC];
    float4 s = make_float4(0.f, 0.f, 0.f, 0.f);
    if (tid < CC) {
        #pragma unroll
        for (int k = 0; k < RQUART; ++k) {
            const float4 pq = partial[(b * CC + tid) * RQUART + k];
            s.x += pq.x; s.y += pq.y; s.z += pq.z; s.w += pq.w;
        }
        gap[tid] = s.w * (1.0f / 65536.0f);         // mean(X_re) == mean(x) exactly
    }
    __syncthreads();
    float y = 0.f;
    if (tid < CC) {
        y = fc_b[tid];
        for (int j = 0; j < CC; ++j) y += gap[j] * fc_w[tid * CC + j];
        yv[tid] = y;
    }
    if (tid < HIDDEN) {
        float z = se_b1[tid];
        for (int j = 0; j < CC; ++j) z += gap[j] * se_w1[tid * CC + j];
        z1[tid] = fmaxf(z, 0.0f);
    }
    __syncthreads();
    __shared__ float ev[CC];
    float e = 0.f;
    if (tid < CC) {
        float mx = -1e30f;
        for (int j = 0; j < CC; ++j) mx = fmaxf(mx, yv[j]);
        e = expf(y - mx);
        ev[tid] = e;
    }
    __syncthreads();
    if (tid < CC) {
        float ssum = 0.f;
        for (int j = 0; j < CC; ++j) ssum += ev[j];
        const float wsm = e / ssum;

        float wse = se_b2[tid];
        for (int h = 0; h < HIDDEN; ++h) wse += z1[h] * se_w2[tid * HIDDEN + h];
        wse = sigmoidf_(wse);
        const float wse2 = gamma_p[0] * wse;

        const float m0 = s.x * (0.5f / 16384.0f) + 1e-6f;
        const float m1 = s.y * (0.5f / 16384.0f) + 1e-6f;
        const float m2 = s.z * (0.5f / 16384.0f) + 1e-6f;
        CParams p;
        const float g0 = sigmoidf_(dir_gate[0 * CC + tid]);
        const float g1 = sigmoidf_(dir_gate[1 * CC + tid]);
        const float g2 = sigmoidf_(dir_gate[2 * CC + tid]);
        p.thr0 = 2.0f * sigmoidf_(theta[0 * CC + tid]) * m0;
        p.thr1 = 2.0f * sigmoidf_(theta[1 * CC + tid]) * m1;
        p.thr2 = 2.0f * sigmoidf_(theta[2 * CC + tid]) * m2;
        p.gA0 = g0; p.gA1 = g1; p.gA2 = g2;
        p.gF0 = 0.5f * g0 * wse2;
        p.gF1 = 0.5f * g1 * wse2;
        p.gF2 = 0.5f * g2 * wse2;
        p.wsm = wsm;
        p.e0q = 0.25f * wse2;
        const float r0 = sub_r[tid * 3 + 0], r1 = sub_r[tid * 3 + 1], r2 = sub_r[tid * 3 + 2];
        const float rm = fmaxf(r0, fmaxf(r1, r2));
        const float e0 = expf(r0 - rm), e1 = expf(r1 - rm), e2 = expf(r2 - rm);
        const float inv = 1.0f / (e0 + e1 + e2);
        const float w0 = e0 * inv, w1 = e1 * inv, w2 = e2 * inv;
        p.ca = 0.5f * (-w0 - w1 + w2);
        p.cb = 0.5f * ( w0 - w1 - w2);
        p.cc = 0.5f * (-w0 + w1 - w2);
        p.cd = 0.5f * ( w0 + w1 + w2);
        p.pad0 = 0.f;
        cbuf[b * CC + tid] = p;
    }
}

// ---------------- Kernel 2: fused attn + final (R7 body, x read once) ----------------
__global__ __launch_bounds__(256) void k_fused(const float* __restrict__ x,
                                               const CParams* __restrict__ cbuf,
                                               float* __restrict__ out) {
    const int b = blockIdx.y;
    const int chunk = blockIdx.x;                 // 0..511
    const int tid = threadIdx.x;
    const int pp = tid & 15;                      // pair 0..15
    const int g  = tid >> 4;                      // channel group 0..15

    __shared__ CParams cp[CC];                    // 8 KB
    __shared__ float red2[16][16][6];             // 6 KB
    __shared__ float att2[16][4];
    {
        const float* src = (const float*)(cbuf + b * CC);
        float* dst = (float*)cp;
        for (int i = tid; i < CC * 16; i += 256) dst[i] = src[i];
    }
    __syncthreads();

    const int p  = chunk * FCHUNK + pp;           // 0..8191
    const int rp = p >> 6, q = p & 63;
    const float* base = x + (size_t)b * CC * HWSZ + (2*rp) * WWW + 4*q;

    float4 st[8], sb[8];                          // register stash: 8 ch x (top,bot)
    float sA0=0, sA1=0, sA2=0, sB0=0, sB1=0, sB2=0;
    #pragma unroll
    for (int ci = 0; ci < 8; ++ci) {
        const int c = g * 8 + ci;
        const float* pc = base + c * HWSZ;
        st[ci] = *(const float4*)(pc);
        sb[ci] = *(const float4*)(pc + WWW);
        const float thr0 = cp[c].thr0, thr1 = cp[c].thr1, thr2 = cp[c].thr2;
        const float gA0 = cp[c].gA0, gA1 = cp[c].gA1, gA2 = cp[c].gA2;
        {   const float a = st[ci].x, b_ = st[ci].y, c_ = sb[ci].x, d = sb[ci].y;
            const float u1 = a + b_, u2 = c_ + d, u3 = a + c_, u4 = b_ + d, u5 = a + d, u6 = b_ + c_;
            sA0 += gA0 * fmaxf(fabsf(u4 - u3) - thr0, 0.f);
            sA1 += gA1 * fmaxf(fabsf(u2 - u1) - thr1, 0.f);
            sA2 += gA2 * fmaxf(fabsf(u5 - u6) - thr2, 0.f);
        }
        {   const float a = st[ci].z, b_ = st[ci].w, c_ = sb[ci].z, d = sb[ci].w;
            const float u1 = a + b_, u2 = c_ + d, u3 = a + c_, u4 = b_ + d, u5 = a + d, u6 = b_ + c_;
            sB0 += gA0 * fmaxf(fabsf(u4 - u3) - thr0, 0.f);
            sB1 += gA1 * fmaxf(fabsf(u2 - u1) - thr1, 0.f);
            sB2 += gA2 * fmaxf(fabsf(u5 - u6) - thr2, 0.f);
        }
    }
    red2[g][pp][0] = sA0; red2[g][pp][1] = sA1; red2[g][pp][2] = sA2;
    red2[g][pp][3] = sB0; red2[g][pp][4] = sB1; red2[g][pp][5] = sB2;
    __syncthreads();

    if (tid < 32) {
        const int pair = tid >> 1, h = tid & 1;   // h=0 -> A, h=1 -> B
        float v0 = 0.f, v1 = 0.f, v2 = 0.f;
        #pragma unroll
        for (int gg = 0; gg < 16; ++gg) {
            v0 += red2[gg][pair][3*h + 0];
            v1 += red2[gg][pair][3*h + 1];
            v2 += red2[gg][pair][3*h + 2];
        }
        v0 *= (0.5f / CC); v1 *= (0.5f / CC); v2 *= (0.5f / CC);
        const float mx = fmaxf(v0, fmaxf(v1, v2));
        const float e0 = expf(v0 - mx), e1 = expf(v1 - mx), e2 = expf(v2 - mx);
        const float inv = 1.0f / (e0 + e1 + e2);
        att2[pair][2*h + 0] = e0 * inv;
        att2[pair][2*h + 1] = e1 * inv;
    }
    __syncthreads();

    const float a0A = att2[pp][0], a1A = att2[pp][1], a2A = 1.0f - a0A - a1A;
    const float a0B = att2[pp][2], a1B = att2[pp][3], a2B = 1.0f - a0B - a1B;

    float* obase = out + (size_t)b * CC * HWSZ + (2*rp) * WWW + 4*q;
    #pragma unroll
    for (int ci = 0; ci < 8; ++ci) {
        const int c = g * 8 + ci;
        const float thr0 = cp[c].thr0, thr1 = cp[c].thr1, thr2 = cp[c].thr2;
        const float gF0 = cp[c].gF0, gF1 = cp[c].gF1, gF2 = cp[c].gF2;
        const float wsm = cp[c].wsm, e0q = cp[c].e0q;
        const float ca = cp[c].ca, cb = cp[c].cb, ccc = cp[c].cc, cd = cp[c].cd;
        const float m0A = a0A * gF0, m1A = a1A * gF1, m2A = a2A * gF2;
        const float m0B = a0B * gF0, m1B = a1B * gF1, m2B = a2B * gF2;
        nfloat4 otop, obot;
        {   const float a = st[ci].x, b_ = st[ci].y, c_ = sb[ci].x, d = sb[ci].y;
            const float u1 = a + b_, u2 = c_ + d, u3 = a + c_, u4 = b_ + d, u5 = a + d, u6 = b_ + c_;
            const float B0 = u4 - u3, B1 = u2 - u1, B2 = u5 - u6;
            const float LL2 = u1 + u2;
            const float s0 = copysignf(fmaxf(fabsf(B0) - thr0, 0.f), B0);
            const float s1 = copysignf(fmaxf(fabsf(B1) - thr1, 0.f), B1);
            const float s2 = copysignf(fmaxf(fabsf(B2) - thr2, 0.f), B2);
            const float Hf = s0*m0A + s1*m1A + s2*m2A;    // = wse2 * H_mix
            const float T  = e0q * LL2;                   // = wse2 * 0.5*LL
            otop.x = fmaf(a , wsm, fmaf(Hf, ca , T));
            otop.y = fmaf(b_, wsm, fmaf(Hf, cb , T));
            obot.x = fmaf(c_, wsm, fmaf(Hf, ccc, T));
            obot.y = fmaf(d , wsm, fmaf(Hf, cd , T));
        }
        {   const float a = st[ci].z, b_ = st[ci].w, c_ = sb[ci].z, d = sb[ci].w;
            const float u1 = a + b_, u2 = c_ + d, u3 = a + c_, u4 = b_ + d, u5 = a + d, u6 = b_ + c_;
            const float B0 = u4 - u3, B1 = u2 - u1, B2 = u5 - u6;
            const float LL2 = u1 + u2;
            const float s0 = copysignf(fmaxf(fabsf(B0) - thr0, 0.f), B0);
            const float s1 = copysignf(fmaxf(fabsf(B1) - thr1, 0.f), B1);
            const float s2 = copysignf(fmaxf(fabsf(B2) - thr2, 0.f), B2);
            const float Hf = s0*m0B + s1*m1B + s2*m2B;
            const float T  = e0q * LL2;
            otop.z = fmaf(a , wsm, fmaf(Hf, ca , T));
            otop.w = fmaf(b_, wsm, fmaf(Hf, cb , T));
            obot.z = fmaf(c_, wsm, fmaf(Hf, ccc, T));
            obot.w = fmaf(d , wsm, fmaf(Hf, cd , T));
        }
        float* po = obase + c * HWSZ;
        __builtin_nontemporal_store(otop, (nfloat4*)(po));
        __builtin_nontemporal_store(obot, (nfloat4*)(po + WWW));
    }
}

extern "C" void kernel_launch(void* const* d_in, const int* in_sizes, int n_in,
                              void* d_out, int out_size, void* d_ws, size_t ws_size,
                              hipStream_t stream) {
    const float* x        = (const float*)d_in[0];
    const float* theta    = (const float*)d_in[1];
    const float* dir_gate = (const float*)d_in[2];
    const float* fc_w     = (const float*)d_in[3];
    const float* fc_b     = (const float*)d_in[4];
    const float* sub_r    = (const float*)d_in[5];
    const float* se_w1    = (const float*)d_in[6];
    const float* se_b1    = (const float*)d_in[7];
    const float* se_w2    = (const float*)d_in[8];
    const float* se_b2    = (const float*)d_in[9];
    const float* gamma_p  = (const float*)d_in[10];
    float* out = (float*)d_out;

    char* ws = (char*)d_ws;
    float4*       partial  = (float4*)(ws);             // 2048 * 16B = 32 KB
    CParams*      cbuf     = (CParams*)(ws + 32768);    // 512 * 64B = 32 KB
    unsigned int* counters = (unsigned int*)(ws + 65536); // 4 * 4B

    hipMemsetAsync(counters, 0, BB * sizeof(unsigned int), stream);
    k_reduce<<<dim3(BB * CC * RQUART), dim3(256), 0, stream>>>(
        x, partial, counters, theta, dir_gate, fc_w, fc_b,
        sub_r, se_w1, se_b1, se_w2, se_b2, gamma_p, cbuf);
    k_fused<<<dim3(NFCHUNK, BB), dim3(256), 0, stream>>>(x, cbuf, out);
}

// Round 14
// 75.213 us; speedup vs baseline: 1.9639x; 1.9639x over previous
//
#include <hip/hip_runtime.h>
#include <math.h>

#define BB 4
#define CC 128
#define HHH 256
#define WWW 256
#define HWSZ (HHH*WWW)      // 65536 elems per (b,c) slice
#define HIDDEN 16
#define NPAIR 8192          // float4-pairs per b-image: 128 row-pairs * 64 float4-cols
#define FCHUNK 16           // pairs per fused block
#define NFCHUNK (NPAIR/FCHUNK)   // 512
#define RQUART 4            // reduce blocks per (b,c)

typedef float nfloat4 __attribute__((ext_vector_type(4)));

// EXACTLY 16 floats = 64 B (LDS copy and ws layout depend on this)
struct CParams {
    float thr0, thr1, thr2;   // 2*sigmoid(theta)*m  (thresholds for UNSCALED bands)
    float gA0, gA1, gA2;      // sigmoid(dir_gate)   (attn path, raw)
    float gF0, gF1, gF2;      // 0.5*g*wse2          (final path, folded)
    float wsm, e0q;           // softmax weight; 0.25*wse2
    float ca, cb, cc, cd;     // 0.5 * idwt sign-combos of w_redis
    float pad0;
};
static_assert(sizeof(CParams) == 64, "CParams must be 64B");

__device__ __forceinline__ float sigmoidf_(float v) { return 1.0f / (1.0f + expf(-v)); }

// ---------------- Kernel 1: per-(b,c) partial reductions ----------------
__global__ __launch_bounds__(256) void k_reduce(const float* __restrict__ x,
                                                float4* __restrict__ partial) {
    const int bq = blockIdx.x;                  // 0..2047
    const int bc = bq >> 2;
    const int quarter = bq & 3;
    const float* base = x + (size_t)bc * HWSZ;
    const int tid = threadIdx.x;
    float a0 = 0.f, a1 = 0.f, a2 = 0.f, sx = 0.f;
    #pragma unroll
    for (int i = 0; i < 8; ++i) {
        const int p = quarter * 2048 + i * 256 + tid;   // 0..8191
        const int r = p >> 6;
        const int q = p & 63;
        const float4 t  = *(const float4*)(base + (2*r)   * WWW + 4*q);
        const float4 bo = *(const float4*)(base + (2*r+1) * WWW + 4*q);
        {   const float a = t.x, b_ = t.y, c_ = bo.x, d = bo.y;
            const float u1 = a + b_, u2 = c_ + d, u3 = a + c_, u4 = b_ + d, u5 = a + d, u6 = b_ + c_;
            a0 += fabsf(u4 - u3);   // |2LH|
            a1 += fabsf(u2 - u1);   // |2HL|
            a2 += fabsf(u5 - u6);   // |2HH|
            sx += u1 + u2;
        }
        {   const float a = t.z, b_ = t.w, c_ = bo.z, d = bo.w;
            const float u1 = a + b_, u2 = c_ + d, u3 = a + c_, u4 = b_ + d, u5 = a + d, u6 = b_ + c_;
            a0 += fabsf(u4 - u3);
            a1 += fabsf(u2 - u1);
            a2 += fabsf(u5 - u6);
            sx += u1 + u2;
        }
    }
    __shared__ float4 red[256];
    red[tid] = make_float4(a0, a1, a2, sx);
    __syncthreads();
    for (int off = 128; off > 0; off >>= 1) {
        if (tid < off) {
            float4 o = red[tid + off];
            red[tid].x += o.x; red[tid].y += o.y; red[tid].z += o.z; red[tid].w += o.w;
        }
        __syncthreads();
    }
    if (tid == 0) partial[bq] = red[0];
}

// ---------------- Kernel 2: tiny — all per-(b,c) params ----------------
__global__ __launch_bounds__(128) void k_params(
    const float4* __restrict__ partial,
    const float* __restrict__ theta, const float* __restrict__ dir_gate,
    const float* __restrict__ fc_w, const float* __restrict__ fc_b,
    const float* __restrict__ sub_r,
    const float* __restrict__ se_w1, const float* __restrict__ se_b1,
    const float* __restrict__ se_w2, const float* __restrict__ se_b2,
    const float* __restrict__ gamma_p,
    CParams* __restrict__ cbuf)
{
    const int b = blockIdx.x;      // 0..3
    const int i = threadIdx.x;     // channel 0..127
    __shared__ float gap[CC];
    __shared__ float z1[HIDDEN];
    __shared__ float red[CC];

    float4 s = make_float4(0.f, 0.f, 0.f, 0.f);
    #pragma unroll
    for (int k = 0; k < RQUART; ++k) {
        const float4 pq = partial[(b * CC + i) * RQUART + k];
        s.x += pq.x; s.y += pq.y; s.z += pq.z; s.w += pq.w;
    }
    gap[i] = s.w * (1.0f / 65536.0f);           // mean(X_re) == mean(x) exactly
    __syncthreads();

    float y = fc_b[i];
    for (int j = 0; j < CC; ++j) y += gap[j] * fc_w[i * CC + j];
    if (i < HIDDEN) {
        float z = se_b1[i];
        for (int j = 0; j < CC; ++j) z += gap[j] * se_w1[i * CC + j];
        z1[i] = fmaxf(z, 0.0f);
    }
    red[i] = y;
    __syncthreads();
    float mx = -1e30f;
    for (int j = 0; j < CC; ++j) mx = fmaxf(mx, red[j]);
    const float e = expf(y - mx);
    __syncthreads();
    red[i] = e;
    __syncthreads();
    float ssum = 0.f;
    for (int j = 0; j < CC; ++j) ssum += red[j];
    const float wsm = e / ssum;

    float wse = se_b2[i];
    for (int h = 0; h < HIDDEN; ++h) wse += z1[h] * se_w2[i * HIDDEN + h];
    wse = sigmoidf_(wse);
    const float wse2 = gamma_p[0] * wse;

    // mean|band| = 0.5/16384 * sum|2*band|
    const float m0 = s.x * (0.5f / 16384.0f) + 1e-6f;
    const float m1 = s.y * (0.5f / 16384.0f) + 1e-6f;
    const float m2 = s.z * (0.5f / 16384.0f) + 1e-6f;
    CParams p;
    const float g0 = sigmoidf_(dir_gate[0 * CC + i]);
    const float g1 = sigmoidf_(dir_gate[1 * CC + i]);
    const float g2 = sigmoidf_(dir_gate[2 * CC + i]);
    p.thr0 = 2.0f * sigmoidf_(theta[0 * CC + i]) * m0;
    p.thr1 = 2.0f * sigmoidf_(theta[1 * CC + i]) * m1;
    p.thr2 = 2.0f * sigmoidf_(theta[2 * CC + i]) * m2;
    p.gA0 = g0; p.gA1 = g1; p.gA2 = g2;
    p.gF0 = 0.5f * g0 * wse2;
    p.gF1 = 0.5f * g1 * wse2;
    p.gF2 = 0.5f * g2 * wse2;
    p.wsm = wsm;
    p.e0q = 0.25f * wse2;
    const float r0 = sub_r[i * 3 + 0], r1 = sub_r[i * 3 + 1], r2 = sub_r[i * 3 + 2];
    const float rm = fmaxf(r0, fmaxf(r1, r2));
    const float e0 = expf(r0 - rm), e1 = expf(r1 - rm), e2 = expf(r2 - rm);
    const float inv = 1.0f / (e0 + e1 + e2);
    const float w0 = e0 * inv, w1 = e1 * inv, w2 = e2 * inv;
    // idwt: out_a = 0.5*LL + 0.5*(-LH' - HL' + HH') etc. -> fold the idwt 0.5 here
    p.ca = 0.5f * (-w0 - w1 + w2);
    p.cb = 0.5f * ( w0 - w1 - w2);
    p.cc = 0.5f * (-w0 + w1 - w2);
    p.cd = 0.5f * ( w0 + w1 + w2);
    p.pad0 = 0.f;
    cbuf[b * CC + i] = p;
}

// ---------------- Kernel 3: fused attn + final, x read ONCE ----------------
// Block = (b, 16 pairs) x 128 channels. 256 threads = 16 groups (8 ch) x 16 pairs.
// Phase 1 loads x into registers + accumulates band sums; LDS reduce + softmax;
// phase 2 recomputes bands from the register stash and writes out.
__global__ __launch_bounds__(256) void k_fused(const float* __restrict__ x,
                                               const CParams* __restrict__ cbuf,
                                               float* __restrict__ out) {
    const int b = blockIdx.y;
    const int chunk = blockIdx.x;                 // 0..511
    const int tid = threadIdx.x;
    const int pp = tid & 15;                      // pair 0..15
    const int g  = tid >> 4;                      // channel group 0..15

    __shared__ CParams cp[CC];                    // 8 KB
    __shared__ float red2[16][16][6];             // 6 KB
    __shared__ float att2[16][4];                 // a0A,a1A,a0B,a1B per pair
    {
        const float* src = (const float*)(cbuf + b * CC);
        float* dst = (float*)cp;
        for (int i = tid; i < CC * 16; i += 256) dst[i] = src[i];
    }
    __syncthreads();

    const int p  = chunk * FCHUNK + pp;           // 0..8191
    const int rp = p >> 6, q = p & 63;
    const float* base = x + (size_t)b * CC * HWSZ + (2*rp) * WWW + 4*q;

    float4 st[8], sb[8];                          // register stash: 8 ch x (top,bot)
    float sA0=0, sA1=0, sA2=0, sB0=0, sB1=0, sB2=0;
    #pragma unroll
    for (int ci = 0; ci < 8; ++ci) {
        const int c = g * 8 + ci;
        const float* pc = base + c * HWSZ;
        st[ci] = *(const float4*)(pc);
        sb[ci] = *(const float4*)(pc + WWW);
        const float thr0 = cp[c].thr0, thr1 = cp[c].thr1, thr2 = cp[c].thr2;
        const float gA0 = cp[c].gA0, gA1 = cp[c].gA1, gA2 = cp[c].gA2;
        {   const float a = st[ci].x, b_ = st[ci].y, c_ = sb[ci].x, d = sb[ci].y;
            const float u1 = a + b_, u2 = c_ + d, u3 = a + c_, u4 = b_ + d, u5 = a + d, u6 = b_ + c_;
            sA0 += gA0 * fmaxf(fabsf(u4 - u3) - thr0, 0.f);
            sA1 += gA1 * fmaxf(fabsf(u2 - u1) - thr1, 0.f);
            sA2 += gA2 * fmaxf(fabsf(u5 - u6) - thr2, 0.f);
        }
        {   const float a = st[ci].z, b_ = st[ci].w, c_ = sb[ci].z, d = sb[ci].w;
            const float u1 = a + b_, u2 = c_ + d, u3 = a + c_, u4 = b_ + d, u5 = a + d, u6 = b_ + c_;
            sB0 += gA0 * fmaxf(fabsf(u4 - u3) - thr0, 0.f);
            sB1 += gA1 * fmaxf(fabsf(u2 - u1) - thr1, 0.f);
            sB2 += gA2 * fmaxf(fabsf(u5 - u6) - thr2, 0.f);
        }
    }
    red2[g][pp][0] = sA0; red2[g][pp][1] = sA1; red2[g][pp][2] = sA2;
    red2[g][pp][3] = sB0; red2[g][pp][4] = sB1; red2[g][pp][5] = sB2;
    __syncthreads();

    if (tid < 32) {
        const int pair = tid >> 1, h = tid & 1;   // h=0 -> A, h=1 -> B
        float v0 = 0.f, v1 = 0.f, v2 = 0.f;
        #pragma unroll
        for (int gg = 0; gg < 16; ++gg) {
            v0 += red2[gg][pair][3*h + 0];
            v1 += red2[gg][pair][3*h + 1];
            v2 += red2[gg][pair][3*h + 2];
        }
        v0 *= (0.5f / CC); v1 *= (0.5f / CC); v2 *= (0.5f / CC);
        const float mx = fmaxf(v0, fmaxf(v1, v2));
        const float e0 = expf(v0 - mx), e1 = expf(v1 - mx), e2 = expf(v2 - mx);
        const float inv = 1.0f / (e0 + e1 + e2);
        att2[pair][2*h + 0] = e0 * inv;
        att2[pair][2*h + 1] = e1 * inv;
    }
    __syncthreads();

    const float a0A = att2[pp][0], a1A = att2[pp][1], a2A = 1.0f - a0A - a1A;
    const float a0B = att2[pp][2], a1B = att2[pp][3], a2B = 1.0f - a0B - a1B;

    float* obase = out + (size_t)b * CC * HWSZ + (2*rp) * WWW + 4*q;
    #pragma unroll
    for (int ci = 0; ci < 8; ++ci) {
        const int c = g * 8 + ci;
        const float thr0 = cp[c].thr0, thr1 = cp[c].thr1, thr2 = cp[c].thr2;
        const float gF0 = cp[c].gF0, gF1 = cp[c].gF1, gF2 = cp[c].gF2;
        const float wsm = cp[c].wsm, e0q = cp[c].e0q;
        const float ca = cp[c].ca, cb = cp[c].cb, ccc = cp[c].cc, cd = cp[c].cd;
        const float m0A = a0A * gF0, m1A = a1A * gF1, m2A = a2A * gF2;
        const float m0B = a0B * gF0, m1B = a1B * gF1, m2B = a2B * gF2;
        nfloat4 otop, obot;
        {   const float a = st[ci].x, b_ = st[ci].y, c_ = sb[ci].x, d = sb[ci].y;
            const float u1 = a + b_, u2 = c_ + d, u3 = a + c_, u4 = b_ + d, u5 = a + d, u6 = b_ + c_;
            const float B0 = u4 - u3, B1 = u2 - u1, B2 = u5 - u6;
            const float LL2 = u1 + u2;
            const float s0 = copysignf(fmaxf(fabsf(B0) - thr0, 0.f), B0);
            const float s1 = copysignf(fmaxf(fabsf(B1) - thr1, 0.f), B1);
            const float s2 = copysignf(fmaxf(fabsf(B2) - thr2, 0.f), B2);
            const float Hf = s0*m0A + s1*m1A + s2*m2A;    // = wse2 * H_mix
            const float T  = e0q * LL2;                   // = wse2 * 0.5*LL
            otop.x = fmaf(a , wsm, fmaf(Hf, ca , T));
            otop.y = fmaf(b_, wsm, fmaf(Hf, cb , T));
            obot.x = fmaf(c_, wsm, fmaf(Hf, ccc, T));
            obot.y = fmaf(d , wsm, fmaf(Hf, cd , T));
        }
        {   const float a = st[ci].z, b_ = st[ci].w, c_ = sb[ci].z, d = sb[ci].w;
            const float u1 = a + b_, u2 = c_ + d, u3 = a + c_, u4 = b_ + d, u5 = a + d, u6 = b_ + c_;
            const float B0 = u4 - u3, B1 = u2 - u1, B2 = u5 - u6;
            const float LL2 = u1 + u2;
            const float s0 = copysignf(fmaxf(fabsf(B0) - thr0, 0.f), B0);
            const float s1 = copysignf(fmaxf(fabsf(B1) - thr1, 0.f), B1);
            const float s2 = copysignf(fmaxf(fabsf(B2) - thr2, 0.f), B2);
            const float Hf = s0*m0B + s1*m1B + s2*m2B;
            const float T  = e0q * LL2;
            otop.z = fmaf(a , wsm, fmaf(Hf, ca , T));
            otop.w = fmaf(b_, wsm, fmaf(Hf, cb , T));
            obot.z = fmaf(c_, wsm, fmaf(Hf, ccc, T));
            obot.w = fmaf(d , wsm, fmaf(Hf, cd , T));
        }
        float* po = obase + c * HWSZ;
        __builtin_nontemporal_store(otop, (nfloat4*)(po));
        __builtin_nontemporal_store(obot, (nfloat4*)(po + WWW));
    }
}

extern "C" void kernel_launch(void* const* d_in, const int* in_sizes, int n_in,
                              void* d_out, int out_size, void* d_ws, size_t ws_size,
                              hipStream_t stream) {
    const float* x        = (const float*)d_in[0];
    const float* theta    = (const float*)d_in[1];
    const float* dir_gate = (const float*)d_in[2];
    const float* fc_w     = (const float*)d_in[3];
    const float* fc_b     = (const float*)d_in[4];
    const float* sub_r    = (const float*)d_in[5];
    const float* se_w1    = (const float*)d_in[6];
    const float* se_b1    = (const float*)d_in[7];
    const float* se_w2    = (const float*)d_in[8];
    const float* se_b2    = (const float*)d_in[9];
    const float* gamma_p  = (const float*)d_in[10];
    float* out = (float*)d_out;

    char* ws = (char*)d_ws;
    float4*  partial = (float4*)(ws);              // 2048 * 16B = 32 KB
    CParams* cbuf    = (CParams*)(ws + 32768);     // 512 * 64B = 32 KB

    k_reduce<<<dim3(BB * CC * RQUART), dim3(256), 0, stream>>>(x, partial);
    k_params<<<dim3(BB), dim3(CC), 0, stream>>>(partial, theta, dir_gate, fc_w, fc_b,
                                                sub_r, se_w1, se_b1, se_w2, se_b2,
                                                gamma_p, cbuf);
    k_fused<<<dim3(NFCHUNK, BB), dim3(256), 0, stream>>>(x, cbuf, out);
}